// Round 1
// baseline (6629.814 us; speedup 1.0000x reference)
//
#include <hip/hip_runtime.h>

// EncoderLSTM: T=512 steps, B=256, Din=33 (y:32 + t:1), H=512, OUT=32.
// Persistent cooperative kernel: 256 WGs = 8 batch-groups (32 rows) x 32 unit-groups (16 units).
// K-extended GEMM per step: gates[32x64] = [h(512)|x(33)|0(31)] @ [W_hh|W_ih|0]^T via bf16 MFMA.
// Cross-WG sync: per-batch-group flags (agent scope), double-buffered bf16 h in workspace.

#define T_STEPS 512
#define BATCH   256
#define HID     512
#define KEXT    576                  // 512 + 33 + 31 pad
#define ROWB    1152                 // KEXT * 2 bytes
#define HOFF    (64 * ROWB)          // W slice: 64 rows -> 73728 B
#define LDS_BYTES (HOFF + 32 * ROWB) // + h tile 32 rows -> 110592 B

typedef __attribute__((ext_vector_type(8))) short short8; // 8 bf16 (4 VGPRs)
typedef __attribute__((ext_vector_type(4))) float f32x4;

__device__ __forceinline__ int swz(int row, int kByte) {
  // XOR-swizzle within each 128B block; ROWB = 9*128 so blocks stay in-row.
  return row * ROWB + (kByte ^ ((row & 7) << 4));
}
__device__ __forceinline__ unsigned short f2bf(float f) { // RNE
  union { float f; unsigned u; } v; v.f = f;
  unsigned r = v.u + 0x7FFFu + ((v.u >> 16) & 1u);
  return (unsigned short)(r >> 16);
}
__device__ __forceinline__ float sigm(float x) { return 1.f / (1.f + __expf(-x)); }
__device__ __forceinline__ float tanh_f(float x) { return 1.f - 2.f / (__expf(2.f * x) + 1.f); }

__global__ void __launch_bounds__(256, 1)
lstm_persist(const float* __restrict__ y, const float* __restrict__ tin,
             const float* __restrict__ Wih, const float* __restrict__ Whh,
             const float* __restrict__ bih, const float* __restrict__ bhh,
             unsigned short* __restrict__ hbuf,   // [2][256][512] bf16
             float* __restrict__ hf32,            // [256][512]
             int* __restrict__ flags)             // [256][16] (64B stride)
{
  __shared__ __align__(16) unsigned char sm[LDS_BYTES];
  const int tid  = threadIdx.x;
  const int wave = tid >> 6, lane = tid & 63;
  const int bid  = blockIdx.x;
  const int wg_m = bid & 7;            // batch-group (XCD-affine: round-robin dispatch)
  const int m0   = wg_m << 5;          // batch base (32 rows)
  const int u0   = (bid >> 3) << 4;    // unit base (16 units)

  // ---- stage W_ext slice into LDS (once): local row c = unit*4 + gate ----
  {
    const int c = tid >> 2, part = tid & 3;             // 64 rows x 4 parts (144 cols each)
    const int rg = ((c & 3) << 9) + u0 + (c >> 2);      // global gate-row = gate*512 + unit
    const float* whrow = Whh + (size_t)rg * HID;
    if (part < 3) {
      const int k0 = part * 144;
      const float4* src = (const float4*)(whrow + k0);
      for (int i = 0; i < 36; ++i) {
        float4 f = src[i];
        uint2 p;
        p.x = (unsigned)f2bf(f.x) | ((unsigned)f2bf(f.y) << 16);
        p.y = (unsigned)f2bf(f.z) | ((unsigned)f2bf(f.w) << 16);
        *(uint2*)&sm[swz(c, (k0 + i * 4) * 2)] = p;
      }
    } else {
      const float4* src = (const float4*)(whrow + 432);
      for (int i = 0; i < 20; ++i) {                    // k 432..511
        float4 f = src[i];
        uint2 p;
        p.x = (unsigned)f2bf(f.x) | ((unsigned)f2bf(f.y) << 16);
        p.y = (unsigned)f2bf(f.z) | ((unsigned)f2bf(f.w) << 16);
        *(uint2*)&sm[swz(c, (432 + i * 4) * 2)] = p;
      }
      uint4 z; z.x = z.y = z.z = z.w = 0;               // zero pad k 544..575
      for (int i = 0; i < 4; ++i) *(uint4*)&sm[swz(c, 1088 + i * 16)] = z;
      const float* wirow = Wih + (size_t)rg * 33;       // x part: k 512..544
      for (int d = 0; d < 32; d += 2) {
        unsigned p = (unsigned)f2bf(wirow[d]) | ((unsigned)f2bf(wirow[d + 1]) << 16);
        *(unsigned*)&sm[swz(c, 1024 + d * 2)] = p;
      }
      *(unsigned short*)&sm[swz(c, 1088)] = f2bf(wirow[32]);
    }
  }
  // zero h-tile pad (k 545..575; t at k=544 rewritten each step)
  if (tid < 128) {
    int row = tid >> 2, i = tid & 3;
    uint4 z; z.x = z.y = z.z = z.w = 0;
    *(uint4*)&sm[HOFF + swz(row, 1088 + i * 16)] = z;
  }

  // per-lane constants
  const int cl   = (wave << 4) + (lane & 15);            // local output col 0..63
  const int rg_l = ((cl & 3) << 9) + u0 + (cl >> 2);
  const float bias = bih[rg_l] + bhh[rg_l];
  const int ug   = u0 + (cl >> 2);                       // global unit of this lane
  const int g    = lane & 3;                             // gate owned by this lane
  const int arow = lane & 15;
  const int kbyl = (lane >> 4) << 4;                     // (lane>>4)*8 elems * 2B
  const int rowbase = ((g >> 1) << 4) + ((lane >> 4) << 2) + ((g & 1) << 1);
  float c0 = 0.f, c1 = 0.f;
  int* const own_flag = flags + bid * 16;

  __syncthreads();

  for (int s = 0; s < T_STEPS; ++s) {
    // ---- wait until all unit-groups of my batch-group published h_s ----
    if (s > 0) {
      if (wave == 0) {
        const int pidx = (((lane & 31) << 3) | wg_m) * 16;
        while (true) {
          int v = __hip_atomic_load(flags + pidx, __ATOMIC_RELAXED, __HIP_MEMORY_SCOPE_AGENT);
          if (__all(v >= s)) break;
          __builtin_amdgcn_s_sleep(4);
        }
        (void)__hip_atomic_load(flags + pidx, __ATOMIC_ACQUIRE, __HIP_MEMORY_SCOPE_AGENT); // inv L1/L2
      }
      __syncthreads();
    }
    // ---- stage h tile (rows m0..m0+31, k 0..511) ----
    {
      const unsigned short* hb_cur = hbuf + ((size_t)(s & 1) * BATCH * HID);
      const int row = tid >> 3, seg = tid & 7;
      const uint4* src = (const uint4*)(hb_cur + (((size_t)(m0 + row)) << 9) + (seg << 6));
      const int base = seg << 7;
      #pragma unroll
      for (int i = 0; i < 8; ++i) {
        uint4 v = src[i];
        *(uint4*)&sm[HOFF + swz(row, base + (i << 4))] = v;
      }
    }
    // ---- stage x tile (k 512..544): x_rev[s] = y_in[511-s] ----
    {
      const int tt = (T_STEPS - 1) - s;
      if (tid < 128) {
        const int row = tid >> 2, part = tid & 3;
        const int b = m0 + row;
        const float* ysrc = y + (((size_t)tt * BATCH + b) << 5) + (part << 3);
        float4 f0 = ((const float4*)ysrc)[0];
        float4 f1 = ((const float4*)ysrc)[1];
        uint4 p;
        p.x = (unsigned)f2bf(f0.x) | ((unsigned)f2bf(f0.y) << 16);
        p.y = (unsigned)f2bf(f0.z) | ((unsigned)f2bf(f0.w) << 16);
        p.z = (unsigned)f2bf(f1.x) | ((unsigned)f2bf(f1.y) << 16);
        p.w = (unsigned)f2bf(f1.z) | ((unsigned)f2bf(f1.w) << 16);
        *(uint4*)&sm[HOFF + swz(row, 1024 + (part << 4))] = p;
        if (part == 3) {
          float tv = tin[(size_t)tt * BATCH + b];
          *(unsigned short*)&sm[HOFF + swz(row, 1088)] = f2bf(tv);
        }
      }
    }
    __syncthreads();

    // ---- gates = [h|x|0] @ Wext^T : 18 K-steps of 16x16x32 bf16 MFMA ----
    f32x4 acc0 = {0.f, 0.f, 0.f, 0.f}, acc1 = {0.f, 0.f, 0.f, 0.f};
    #pragma unroll
    for (int ks = 0; ks < 18; ++ks) {
      const int kB = (ks << 6) + kbyl;
      short8 a0 = *(const short8*)&sm[HOFF + swz(arow, kB)];
      short8 a1 = *(const short8*)&sm[HOFF + swz(arow + 16, kB)];
      short8 bb = *(const short8*)&sm[swz(cl, kB)];
      acc0 = __builtin_amdgcn_mfma_f32_16x16x32_bf16(a0, bb, acc0, 0, 0, 0);
      acc1 = __builtin_amdgcn_mfma_f32_16x16x32_bf16(a1, bb, acc1, 0, 0, 0);
    }

    // ---- epilogue: 4-lane butterfly to gather i/f/g/o, LSTM update ----
    float vals[8];
    #pragma unroll
    for (int r = 0; r < 4; ++r) { vals[r] = acc0[r] + bias; vals[4 + r] = acc1[r] + bias; }
    float sh1[8], sh2[8], sh3[8];
    #pragma unroll
    for (int j = 0; j < 8; ++j) {
      sh1[j] = __shfl_xor(vals[j], 1);
      sh2[j] = __shfl_xor(vals[j], 2);
      sh3[j] = __shfl_xor(vals[j], 3);
    }
    // lane with gate g handles combos j = 2g, 2g+1; gate q comes from shfl_xor dist (q^g)
    float iv0, fv0, gv0, ov0, iv1, fv1, gv1, ov1;
    if (g == 0)      { iv0=vals[0]; fv0=sh1[0]; gv0=sh2[0]; ov0=sh3[0];
                       iv1=vals[1]; fv1=sh1[1]; gv1=sh2[1]; ov1=sh3[1]; }
    else if (g == 1) { iv0=sh1[2];  fv0=vals[2];gv0=sh3[2]; ov0=sh2[2];
                       iv1=sh1[3];  fv1=vals[3];gv1=sh3[3]; ov1=sh2[3]; }
    else if (g == 2) { iv0=sh2[4];  fv0=sh3[4]; gv0=vals[4];ov0=sh1[4];
                       iv1=sh2[5];  fv1=sh3[5]; gv1=vals[5];ov1=sh1[5]; }
    else             { iv0=sh3[6];  fv0=sh2[6]; gv0=sh1[6]; ov0=vals[6];
                       iv1=sh3[7];  fv1=sh2[7]; gv1=sh1[7]; ov1=vals[7]; }

    c0 = sigm(fv0) * c0 + sigm(iv0) * tanh_f(gv0);
    float h0 = sigm(ov0) * tanh_f(c0);
    c1 = sigm(fv1) * c1 + sigm(iv1) * tanh_f(gv1);
    float h1 = sigm(ov1) * tanh_f(c1);

    unsigned short* hb_next = hbuf + ((size_t)((s + 1) & 1) * BATCH * HID);
    const int b0 = m0 + rowbase, b1 = b0 + 1;
    hb_next[((size_t)b0 << 9) + ug] = f2bf(h0);
    hb_next[((size_t)b1 << 9) + ug] = f2bf(h1);
    if (s == T_STEPS - 1) {
      hf32[((size_t)b0 << 9) + ug] = h0;
      hf32[((size_t)b1 << 9) + ug] = h1;
    }

    __syncthreads();            // compiler drains vmcnt(0) before s_barrier
    if (tid == 0) {
      __threadfence();          // agent-scope release (L2 writeback of h slice)
      __hip_atomic_store(own_flag, s + 1, __ATOMIC_RELAXED, __HIP_MEMORY_SCOPE_AGENT);
    }
  }
}

// out[b][o] = sum_j hf32[b][j] * W_lin[o][j] + b_lin[o]
__global__ void __launch_bounds__(64)
out_proj(const float* __restrict__ hf, const float* __restrict__ Wl,
         const float* __restrict__ bl, float* __restrict__ out)
{
  const int b = blockIdx.x, l = threadIdx.x;
  const int o = l & 31, half = l >> 5;
  const float4* hrow = (const float4*)(hf + ((size_t)b << 9) + (half << 8));
  const float4* wrow = (const float4*)(Wl + ((size_t)o << 9) + (half << 8));
  float acc = 0.f;
  #pragma unroll 8
  for (int j = 0; j < 64; ++j) {
    float4 hv = hrow[j], wv = wrow[j];
    acc += hv.x * wv.x + hv.y * wv.y + hv.z * wv.z + hv.w * wv.w;
  }
  acc += __shfl_xor(acc, 32);
  if (l < 32) out[(b << 5) + o] = acc + bl[o];
}

extern "C" void kernel_launch(void* const* d_in, const int* in_sizes, int n_in,
                              void* d_out, int out_size, void* d_ws, size_t ws_size,
                              hipStream_t stream) {
  const float* y    = (const float*)d_in[0];
  const float* tin  = (const float*)d_in[1];
  const float* Wih  = (const float*)d_in[2];
  const float* Whh  = (const float*)d_in[3];
  const float* bih  = (const float*)d_in[4];
  const float* bhh  = (const float*)d_in[5];
  const float* Wlin = (const float*)d_in[6];
  const float* blin = (const float*)d_in[7];
  float* out = (float*)d_out;

  unsigned char* ws = (unsigned char*)d_ws;
  unsigned short* hbuf = (unsigned short*)ws;        // 2*256*512*2B = 524288
  float* hf32 = (float*)(ws + 524288);               // 256*512*4B   = 524288
  int* flags  = (int*)(ws + 1048576);                // 256*16*4B    = 16384

  hipMemsetAsync(hbuf, 0, 262144, stream);           // h_0 = 0 (buffer 0 only)
  hipMemsetAsync(flags, 0, 16384, stream);           // reset flags every launch

  void* args[] = { (void*)&y, (void*)&tin, (void*)&Wih, (void*)&Whh,
                   (void*)&bih, (void*)&bhh, (void*)&hbuf, (void*)&hf32, (void*)&flags };
  hipLaunchCooperativeKernel((const void*)lstm_persist, dim3(256), dim3(256),
                             args, 0, stream);
  out_proj<<<dim3(256), dim3(64), 0, stream>>>(hf32, Wlin, blin, out);
}

// Round 2
// 1801.617 us; speedup vs baseline: 3.6799x; 3.6799x over previous
//
#include <hip/hip_runtime.h>

// EncoderLSTM: T=512 steps, B=256, Din=33 (y:32 + t:1), H=512, OUT=32.
// Persistent cooperative kernel: 256 WGs = 8 batch-groups (32 rows) x 32 unit-groups (16 units).
// K-extended GEMM per step: gates[32x64] = [h(512)|x(33)|0] @ [W_hh|W_ih|0]^T via bf16 MFMA.
// Cross-WG h exchange entirely via agent-scope ATOMIC loads/stores (IF-coherent point):
// no __threadfence / acquire fences -> no buffer_wbl2 / buffer_inv L2 walks.

#define T_STEPS 512
#define BATCH   256
#define HID     512
#define RSTRIDE 1168                  // LDS row stride bytes (292 banks % 32 = 4 -> no aliasing)
#define GSTRIDE 1024                  // global h-image row stride bytes (512 units * 2B)
#define HOFF    (64 * RSTRIDE)        // W slice: 64 rows -> 74752 B
#define LDS_BYTES (96 * RSTRIDE)      // + h tile 32 rows -> 112128 B
#define IMG_BYTES (BATCH * GSTRIDE)   // 262144 B per buffer

typedef __attribute__((ext_vector_type(8))) short short8; // 8 bf16 (4 VGPRs)
typedef __attribute__((ext_vector_type(4))) float f32x4;

__device__ __forceinline__ unsigned short f2bf(float f) { // RNE
  union { float f; unsigned u; } v; v.f = f;
  unsigned r = v.u + 0x7FFFu + ((v.u >> 16) & 1u);
  return (unsigned short)(r >> 16);
}
__device__ __forceinline__ float sigm(float x) { return 1.f / (1.f + __expf(-x)); }
__device__ __forceinline__ float tanh_f(float x) { return 1.f - 2.f / (__expf(2.f * x) + 1.f); }

__global__ void __launch_bounds__(256, 1)
lstm_persist(const float* __restrict__ y, const float* __restrict__ tin,
             const float* __restrict__ Wih, const float* __restrict__ Whh,
             const float* __restrict__ bih, const float* __restrict__ bhh,
             unsigned char* __restrict__ img,    // [2][256][1024] bf16 h-image
             float* __restrict__ hf32,           // [256][512]
             int* __restrict__ flags)            // [256][16] (64B stride)
{
  __shared__ __align__(16) unsigned char sm[LDS_BYTES];
  const int tid  = threadIdx.x;
  const int wave = tid >> 6, lane = tid & 63;
  const int bid  = blockIdx.x;
  const int wg_m = bid & 7;            // batch-group
  const int m0   = wg_m << 5;          // batch base (32 rows)
  const int u0   = (bid >> 3) << 4;    // unit base (16 units)

  // ---- stage W_ext slice into LDS (once): local row c = unit*4 + gate ----
  {
    const int c = tid >> 2, part = tid & 3;             // 64 rows x 4 parts (128 floats each)
    const int rg = ((c & 3) << 9) + u0 + (c >> 2);      // global gate-row = gate*512 + unit
    const float* whrow = Whh + (size_t)rg * HID;
    const int k0 = part << 7;                           // element base
    const float4* src = (const float4*)(whrow + k0);
    #pragma unroll
    for (int i = 0; i < 32; ++i) {
      float4 f = src[i];
      uint2 p2;
      p2.x = (unsigned)f2bf(f.x) | ((unsigned)f2bf(f.y) << 16);
      p2.y = (unsigned)f2bf(f.z) | ((unsigned)f2bf(f.w) << 16);
      *(uint2*)&sm[c * RSTRIDE + ((k0 + i * 4) << 1)] = p2;
    }
    if (part == 3) {
      const float* wirow = Wih + (size_t)rg * 33;       // x weights: elems 512..543
      for (int d = 0; d < 32; d += 2) {
        unsigned p = (unsigned)f2bf(wirow[d]) | ((unsigned)f2bf(wirow[d + 1]) << 16);
        *(unsigned*)&sm[c * RSTRIDE + 1024 + (d << 1)] = p;
      }
      *(unsigned short*)&sm[c * RSTRIDE + 1088] = f2bf(wirow[32]);  // t weight (elem 544)
      *(unsigned short*)&sm[c * RSTRIDE + 1090] = 0;                // zero pad 1090..1151
      *(unsigned*)&sm[c * RSTRIDE + 1092] = 0;
      uint4 z; z.x = z.y = z.z = z.w = 0;
      *(uint4*)&sm[c * RSTRIDE + 1096] = z;
      *(uint4*)&sm[c * RSTRIDE + 1112] = z;
      *(uint4*)&sm[c * RSTRIDE + 1128] = z;
      *(uint4*)&sm[c * RSTRIDE + 1144] = z;
    }
  }
  // zero h-tile K-pad (bytes 1104..1151; 1088..1103 rewritten each step) — once
  if (tid < 128) {
    int row = tid >> 2, i = tid & 3;
    if (i < 3) {
      uint4 z; z.x = z.y = z.z = z.w = 0;
      *(uint4*)&sm[HOFF + row * RSTRIDE + 1104 + i * 16] = z;
    }
  }

  // per-lane constants
  const int cl   = (wave << 4) + (lane & 15);            // local output col 0..63
  const int rg_l = ((cl & 3) << 9) + u0 + (cl >> 2);
  const float bias = bih[rg_l] + bhh[rg_l];
  const int ug   = u0 + (cl >> 2);                       // global unit of this lane
  const int g    = lane & 3;                             // gate owned by this lane
  const int arow = lane & 15;
  const int kbyl = (lane >> 4) << 4;
  const int rowbase = ((g >> 1) << 4) + ((lane >> 4) << 2) + ((g & 1) << 1);
  float c0 = 0.f, c1 = 0.f;
  int* const own_flag = flags + bid * 16;

  // h-staging addressing: row = tid>>3, 8 threads/row, 128B/thread (u64-interleaved)
  const int hrow = tid >> 3, hl8 = tid & 7;

  __syncthreads();

  for (int s = 0; s < T_STEPS; ++s) {
    // ---- stage x tile (elems 512..544): x_rev[s] = y_in[511-s]; no h dependency ----
    {
      const int tt = (T_STEPS - 1) - s;
      if (tid < 128) {
        const int row = tid >> 2, part = tid & 3;
        const int b = m0 + row;
        const float* ysrc = y + (((size_t)tt * BATCH + b) << 5) + (part << 3);
        float4 f0 = ((const float4*)ysrc)[0];
        float4 f1 = ((const float4*)ysrc)[1];
        uint4 p;
        p.x = (unsigned)f2bf(f0.x) | ((unsigned)f2bf(f0.y) << 16);
        p.y = (unsigned)f2bf(f0.z) | ((unsigned)f2bf(f0.w) << 16);
        p.z = (unsigned)f2bf(f1.x) | ((unsigned)f2bf(f1.y) << 16);
        p.w = (unsigned)f2bf(f1.z) | ((unsigned)f2bf(f1.w) << 16);
        *(uint4*)&sm[HOFF + row * RSTRIDE + 1024 + (part << 4)] = p;
        if (part == 3) {
          float tv = tin[(size_t)tt * BATCH + b];
          uint4 tz; tz.x = (unsigned)f2bf(tv); tz.y = tz.z = tz.w = 0;
          *(uint4*)&sm[HOFF + row * RSTRIDE + 1088] = tz;   // t + zeros 1090..1103
        }
      }
    }
    // ---- wait until all unit-groups of my batch-group published h_s ----
    if (s > 0) {
      if (wave == 0) {
        int* p = flags + ((((lane & 31) << 3) | wg_m) << 4);
        while (true) {
          int v = __hip_atomic_load(p, __ATOMIC_RELAXED, __HIP_MEMORY_SCOPE_AGENT);
          if (__all(v >= s)) break;
          __builtin_amdgcn_s_sleep(1);
        }
      }
      __syncthreads();
    }
    // ---- stage h tile: agent-atomic u64 loads (IF-coherent), then LDS writes ----
    {
      const unsigned char* gsrc = img + (size_t)(s & 1) * IMG_BYTES + (size_t)(m0 + hrow) * GSTRIDE;
      unsigned long long v[16];
      #pragma unroll
      for (int i = 0; i < 16; ++i)
        v[i] = __hip_atomic_load((const unsigned long long*)(gsrc + (hl8 << 3) + (i << 6)),
                                 __ATOMIC_RELAXED, __HIP_MEMORY_SCOPE_AGENT);
      #pragma unroll
      for (int i = 0; i < 16; ++i)
        *(unsigned long long*)&sm[HOFF + hrow * RSTRIDE + (hl8 << 3) + (i << 6)] = v[i];
    }
    __syncthreads();

    // ---- gates = [h|x|0] @ Wext^T : 18 K-steps of 16x16x32 bf16 MFMA ----
    f32x4 acc0 = {0.f, 0.f, 0.f, 0.f}, acc1 = {0.f, 0.f, 0.f, 0.f};
    #pragma unroll
    for (int ks = 0; ks < 18; ++ks) {
      const int kB = (ks << 6) + kbyl;
      short8 a0 = *(const short8*)&sm[HOFF + arow * RSTRIDE + kB];
      short8 a1 = *(const short8*)&sm[HOFF + (arow + 16) * RSTRIDE + kB];
      short8 bb = *(const short8*)&sm[cl * RSTRIDE + kB];
      acc0 = __builtin_amdgcn_mfma_f32_16x16x32_bf16(a0, bb, acc0, 0, 0, 0);
      acc1 = __builtin_amdgcn_mfma_f32_16x16x32_bf16(a1, bb, acc1, 0, 0, 0);
    }

    // ---- epilogue: 4-lane butterfly to gather i/f/g/o, LSTM update ----
    float vals[8];
    #pragma unroll
    for (int r = 0; r < 4; ++r) { vals[r] = acc0[r] + bias; vals[4 + r] = acc1[r] + bias; }
    float sh1[8], sh2[8], sh3[8];
    #pragma unroll
    for (int j = 0; j < 8; ++j) {
      sh1[j] = __shfl_xor(vals[j], 1);
      sh2[j] = __shfl_xor(vals[j], 2);
      sh3[j] = __shfl_xor(vals[j], 3);
    }
    float iv0, fv0, gv0, ov0, iv1, fv1, gv1, ov1;
    if (g == 0)      { iv0=vals[0]; fv0=sh1[0]; gv0=sh2[0]; ov0=sh3[0];
                       iv1=vals[1]; fv1=sh1[1]; gv1=sh2[1]; ov1=sh3[1]; }
    else if (g == 1) { iv0=sh1[2];  fv0=vals[2];gv0=sh3[2]; ov0=sh2[2];
                       iv1=sh1[3];  fv1=vals[3];gv1=sh3[3]; ov1=sh2[3]; }
    else if (g == 2) { iv0=sh2[4];  fv0=sh3[4]; gv0=vals[4];ov0=sh1[4];
                       iv1=sh2[5];  fv1=sh3[5]; gv1=vals[5];ov1=sh1[5]; }
    else             { iv0=sh3[6];  fv0=sh2[6]; gv0=sh1[6]; ov0=vals[6];
                       iv1=sh3[7];  fv1=sh2[7]; gv1=sh1[7]; ov1=vals[7]; }

    c0 = sigm(fv0) * c0 + sigm(iv0) * tanh_f(gv0);
    float h0 = sigm(ov0) * tanh_f(c0);
    c1 = sigm(fv1) * c1 + sigm(iv1) * tanh_f(gv1);
    float h1 = sigm(ov1) * tanh_f(c1);

    // ---- publish h_{s+1}: agent-atomic 2B stores into the other image buffer ----
    {
      unsigned char* gnext = img + (size_t)((s + 1) & 1) * IMG_BYTES;
      const int b0 = m0 + rowbase, b1 = b0 + 1;
      __hip_atomic_store((unsigned short*)(gnext + (size_t)b0 * GSTRIDE + (ug << 1)),
                         f2bf(h0), __ATOMIC_RELAXED, __HIP_MEMORY_SCOPE_AGENT);
      __hip_atomic_store((unsigned short*)(gnext + (size_t)b1 * GSTRIDE + (ug << 1)),
                         f2bf(h1), __ATOMIC_RELAXED, __HIP_MEMORY_SCOPE_AGENT);
      if (s == T_STEPS - 1) {
        hf32[((size_t)b0 << 9) + ug] = h0;
        hf32[((size_t)b1 << 9) + ug] = h1;
      }
    }

    __syncthreads();   // each wave drains vmcnt(0) before s_barrier -> all h stores complete
    if (tid == 0)
      __hip_atomic_store(own_flag, s + 1, __ATOMIC_RELAXED, __HIP_MEMORY_SCOPE_AGENT);
  }
}

// out[b][o] = sum_j hf32[b][j] * W_lin[o][j] + b_lin[o]
__global__ void __launch_bounds__(64)
out_proj(const float* __restrict__ hf, const float* __restrict__ Wl,
         const float* __restrict__ bl, float* __restrict__ out)
{
  const int b = blockIdx.x, l = threadIdx.x;
  const int o = l & 31, half = l >> 5;
  const float4* hrow = (const float4*)(hf + ((size_t)b << 9) + (half << 8));
  const float4* wrow = (const float4*)(Wl + ((size_t)o << 9) + (half << 8));
  float acc = 0.f;
  #pragma unroll 8
  for (int j = 0; j < 64; ++j) {
    float4 hv = hrow[j], wv = wrow[j];
    acc += hv.x * wv.x + hv.y * wv.y + hv.z * wv.z + hv.w * wv.w;
  }
  acc += __shfl_xor(acc, 32);
  if (l < 32) out[(b << 5) + o] = acc + bl[o];
}

extern "C" void kernel_launch(void* const* d_in, const int* in_sizes, int n_in,
                              void* d_out, int out_size, void* d_ws, size_t ws_size,
                              hipStream_t stream) {
  const float* y    = (const float*)d_in[0];
  const float* tin  = (const float*)d_in[1];
  const float* Wih  = (const float*)d_in[2];
  const float* Whh  = (const float*)d_in[3];
  const float* bih  = (const float*)d_in[4];
  const float* bhh  = (const float*)d_in[5];
  const float* Wlin = (const float*)d_in[6];
  const float* blin = (const float*)d_in[7];
  float* out = (float*)d_out;

  unsigned char* ws = (unsigned char*)d_ws;
  unsigned char* img = ws;                           // 2*256*1024B = 524288
  float* hf32 = (float*)(ws + 524288);               // 256*512*4B  = 524288
  int* flags  = (int*)(ws + 1048576);                // 256*16*4B   = 16384

  hipMemsetAsync(img, 0, IMG_BYTES, stream);         // h_0 = 0 (buffer 0 only)
  hipMemsetAsync(flags, 0, 16384, stream);           // reset flags every launch

  void* args[] = { (void*)&y, (void*)&tin, (void*)&Wih, (void*)&Whh,
                   (void*)&bih, (void*)&bhh, (void*)&img, (void*)&hf32, (void*)&flags };
  hipLaunchCooperativeKernel((const void*)lstm_persist, dim3(256), dim3(256),
                             args, 0, stream);
  out_proj<<<dim3(256), dim3(64), 0, stream>>>(hf32, Wlin, blin, out);
}